// Round 1
// baseline (42697.983 us; speedup 1.0000x reference)
//
#include <hip/hip_runtime.h>
#include <stdint.h>

typedef short bf16x8 __attribute__((ext_vector_type(8)));
typedef float f32x4 __attribute__((ext_vector_type(4)));
typedef unsigned short u16;

__device__ __forceinline__ u16 f2bf(float f) {
    unsigned int u = __float_as_uint(f);
    u = (u + 0x7FFFu + ((u >> 16) & 1u)) >> 16;
    return (u16)u;
}
__device__ __forceinline__ float bf2f(u16 h) {
    return __uint_as_float(((unsigned int)h) << 16);
}
__device__ __forceinline__ float sigm(float x) { return 1.f / (1.f + __expf(-x)); }
__device__ __forceinline__ float tanh_fast(float x) {
    // tanh(x) = 1 - 2/(exp(2x)+1); saturates correctly at +-inf
    return 1.f - 2.f / (__expf(2.f * x) + 1.f);
}

// ---------------------------------------------------------------------------
// K0: transpose fp32 [1024][4096] weight -> bf16 [4096][1024] (K-contiguous)
// ---------------------------------------------------------------------------
__global__ void transpose_w(const float* __restrict__ src, u16* __restrict__ dst)
{
    __shared__ float tile[32][33];
    const int gx = blockIdx.x;   // over 4096/32
    const int gy = blockIdx.y;   // over 1024/32
    const int tx = threadIdx.x;  // 0..31
    const int ty = threadIdx.y;  // 0..7
    #pragma unroll
    for (int i = 0; i < 4; ++i) {
        const int row = gy * 32 + ty + i * 8;
        tile[ty + i * 8][tx] = src[(size_t)row * 4096 + gx * 32 + tx];
    }
    __syncthreads();
    #pragma unroll
    for (int i = 0; i < 4; ++i) {
        const int row = gx * 32 + ty + i * 8;
        dst[(size_t)row * 1024 + gy * 32 + tx] = f2bf(tile[tx][ty + i * 8]);
    }
}

// ---------------------------------------------------------------------------
// K1: convert input chunk fp32 [B][T][D] -> bf16 rows r = t_local*32 + b
// ---------------------------------------------------------------------------
__global__ void convert_inputs(const float* __restrict__ in, u16* __restrict__ A, const int t0)
{
    const int r = blockIdx.x;          // t*32 + b
    const int t = r >> 5, b = r & 31;
    const int d = threadIdx.x << 2;
    const float4 v = *(const float4*)(in + ((size_t)b * 2048 + t0 + t) * 1024 + d);
    ushort4 o = make_ushort4(f2bf(v.x), f2bf(v.y), f2bf(v.z), f2bf(v.w));
    *(ushort4*)(A + (size_t)r * 1024 + d) = o;
}

// ---------------------------------------------------------------------------
// K2: xw[r][g] = sum_k A[r][k] * WiT[g][k] + bias[g]   (bf16 in, bf16 out)
// 128x128 tile, BK=32, 4 waves each 64x64, mfma 16x16x32 bf16
// ---------------------------------------------------------------------------
__launch_bounds__(256)
__global__ void gemm_xw(const u16* __restrict__ A, const u16* __restrict__ B,
                        const float* __restrict__ bias, u16* __restrict__ C)
{
    __shared__ u16 As[128 * 32];
    __shared__ u16 Bs[128 * 32];
    const int bm = blockIdx.x >> 5;
    const int bn = blockIdx.x & 31;
    const int tid = threadIdx.x;
    const int wave = tid >> 6, lane = tid & 63;
    const int wr = wave >> 1, wc = wave & 1;
    const int c16 = lane & 15, quad = lane >> 4;

    f32x4 acc[4][4];
    #pragma unroll
    for (int i = 0; i < 4; ++i)
        #pragma unroll
        for (int j = 0; j < 4; ++j) acc[i][j] = (f32x4){0.f, 0.f, 0.f, 0.f};

    const int srow = tid >> 1;
    const int scol = (tid & 1) << 4;
    const u16* Ag = A + (size_t)(bm * 128 + srow) * 1024 + scol;
    const u16* Bg = B + (size_t)(bn * 128 + srow) * 1024 + scol;
    uint4* AsW = (uint4*)(As + srow * 32 + scol);
    uint4* BsW = (uint4*)(Bs + srow * 32 + scol);

    for (int kt = 0; kt < 32; ++kt) {
        const uint4* ag = (const uint4*)(Ag + kt * 32);
        const uint4* bg = (const uint4*)(Bg + kt * 32);
        const uint4 a0 = ag[0], a1 = ag[1];
        const uint4 b0 = bg[0], b1 = bg[1];
        __syncthreads();
        AsW[0] = a0; AsW[1] = a1;
        BsW[0] = b0; BsW[1] = b1;
        __syncthreads();
        bf16x8 af[4], bfr[4];
        #pragma unroll
        for (int mt = 0; mt < 4; ++mt)
            af[mt] = *(const bf16x8*)(As + (wr * 64 + mt * 16 + c16) * 32 + quad * 8);
        #pragma unroll
        for (int nt = 0; nt < 4; ++nt)
            bfr[nt] = *(const bf16x8*)(Bs + (wc * 64 + nt * 16 + c16) * 32 + quad * 8);
        #pragma unroll
        for (int mt = 0; mt < 4; ++mt)
            #pragma unroll
            for (int nt = 0; nt < 4; ++nt)
                acc[mt][nt] = __builtin_amdgcn_mfma_f32_16x16x32_bf16(af[mt], bfr[nt], acc[mt][nt], 0, 0, 0);
    }
    #pragma unroll
    for (int nt = 0; nt < 4; ++nt) {
        const int g = bn * 128 + wc * 64 + nt * 16 + c16;
        const float bv = bias[g];
        #pragma unroll
        for (int mt = 0; mt < 4; ++mt) {
            const int r0 = bm * 128 + wr * 64 + mt * 16 + quad * 4;
            #pragma unroll
            for (int reg = 0; reg < 4; ++reg)
                C[(size_t)(r0 + reg) * 4096 + g] = f2bf(acc[mt][nt][reg] + bv);
        }
    }
}

// ---------------------------------------------------------------------------
// K3: persistent recurrence. 256 WGs x 256 thr, 1 WG/CU, co-resident.
// WG w owns hidden units u0..u0+3 (u0=4w) => z cols {q*1024+u0+r}.
// Wh fragments persistent in registers; h read direct-from-global in
// MFMA A-layout (k-packed: elem (b,u) at (u/8*32+b)*8 + u%8).
// Custom 2-level device-scope barrier per step.
// ---------------------------------------------------------------------------
__launch_bounds__(256)
__global__ void lstm_rec(const u16* __restrict__ xw, const u16* __restrict__ whT,
                         u16* __restrict__ h_hist, float* __restrict__ hist32,
                         float* __restrict__ c_buf, unsigned int* __restrict__ ctrl,
                         const int Tc)
{
    const int w = blockIdx.x;
    const int tid = threadIdx.x;
    const int wave = tid >> 6, lane = tid & 63;
    const int quad = lane >> 4, c16 = lane & 15;
    const int u0 = w << 2;

    // persistent B fragments: local col c16 = q*4+r -> WhT row q*1024+u0+r,
    // wave handles K slice [256*wave, 256*wave+256)
    bf16x8 Breg[8];
    {
        const int q = c16 >> 2, r = c16 & 3;
        const u16* bp = whT + (size_t)(q * 1024 + u0 + r) * 1024 + wave * 256 + quad * 8;
        #pragma unroll
        for (int ks = 0; ks < 8; ++ks) Breg[ks] = *(const bf16x8*)(bp + ks * 32);
    }

    const int eb = tid & 31, eu = tid >> 5;  // epilogue (batch, unit) for tid<128
    float cst = 0.f;
    if (tid < 128) cst = c_buf[eb * 1024 + u0 + eu];

    __shared__ float red[4][32][17];
    __shared__ u16 hout[32][4];

    const int o_out = w >> 1;
    const int sub = (w & 1) << 2;

    for (int t = 0; t < Tc; ++t) {
        // prefetch xw gate values (independent of h)
        float xv[4];
        if (tid < 128) {
            const u16* xp = xw + (size_t)(t * 32 + eb) * 4096 + u0 + eu;
            xv[0] = bf2f(xp[0]);
            xv[1] = bf2f(xp[1024]);
            xv[2] = bf2f(xp[2048]);
            xv[3] = bf2f(xp[3072]);
        }
        const u16* hsrc = h_hist + (size_t)t * 32768;
        f32x4 acc0 = (f32x4){0.f, 0.f, 0.f, 0.f};
        f32x4 acc1 = (f32x4){0.f, 0.f, 0.f, 0.f};
        #pragma unroll
        for (int ks = 0; ks < 8; ++ks) {
            const int octet = wave * 32 + ks * 4 + quad;
            const bf16x8 a0 = *(const bf16x8*)(hsrc + (octet * 32 + c16) * 8);
            const bf16x8 a1 = *(const bf16x8*)(hsrc + (octet * 32 + 16 + c16) * 8);
            acc0 = __builtin_amdgcn_mfma_f32_16x16x32_bf16(a0, Breg[ks], acc0, 0, 0, 0);
            acc1 = __builtin_amdgcn_mfma_f32_16x16x32_bf16(a1, Breg[ks], acc1, 0, 0, 0);
        }
        // K-split partials -> LDS (C layout: col=c16, row=quad*4+reg)
        #pragma unroll
        for (int reg = 0; reg < 4; ++reg) {
            red[wave][quad * 4 + reg][c16] = acc0[reg];
            red[wave][16 + quad * 4 + reg][c16] = acc1[reg];
        }
        __syncthreads();
        if (tid < 128) {
            float z[4];
            #pragma unroll
            for (int q = 0; q < 4; ++q) {
                const int c = (q << 2) + eu;
                z[q] = red[0][eb][c] + red[1][eb][c] + red[2][eb][c] + red[3][eb][c] + xv[q];
            }
            const float ig = sigm(z[0]);
            const float fg = sigm(z[1]);
            const float gg = tanh_fast(z[2]);
            const float og = sigm(z[3]);
            cst = fg * cst + ig * gg;
            const float h = og * tanh_fast(cst);
            hist32[(size_t)(t * 1024 + u0 + eu) * 32 + eb] = h;  // coalesced [t][u][b]
            hout[eb][eu] = f2bf(h);
        }
        __syncthreads();
        if (tid < 32) {  // publish bf16 slice in k-packed layout
            const uint2 v = *(const uint2*)(&hout[tid][0]);
            *(uint2*)(h_hist + (size_t)(t + 1) * 32768 + (o_out * 32 + tid) * 8 + sub) = v;
        }
        __syncthreads();
        if (tid == 0) {
            __threadfence();
            const unsigned int target = (unsigned int)(t + 1);
            const unsigned int a = __hip_atomic_fetch_add(&ctrl[(w & 7) * 32], 1u,
                                                          __ATOMIC_ACQ_REL, __HIP_MEMORY_SCOPE_AGENT);
            if (a == 32u * target - 1u) {
                const unsigned int m = __hip_atomic_fetch_add(&ctrl[256], 1u,
                                                              __ATOMIC_ACQ_REL, __HIP_MEMORY_SCOPE_AGENT);
                if (m == 8u * target - 1u) {
                    __hip_atomic_store(&ctrl[288], target, __ATOMIC_RELEASE, __HIP_MEMORY_SCOPE_AGENT);
                }
            }
            while (__hip_atomic_load(&ctrl[288], __ATOMIC_ACQUIRE, __HIP_MEMORY_SCOPE_AGENT) < target) {
                __builtin_amdgcn_s_sleep(1);
            }
        }
        __syncthreads();
    }
    if (tid < 128) c_buf[eb * 1024 + u0 + eu] = cst;
}

// ---------------------------------------------------------------------------
// K4: emit d_out[b][t][u] fp32 from hist32[t][u][b] via LDS transpose
// ---------------------------------------------------------------------------
__launch_bounds__(256)
__global__ void emit_out(const float* __restrict__ hist32, float* __restrict__ out, const int t0)
{
    __shared__ float tile[256][33];
    const int t = blockIdx.x;
    const int tid = threadIdx.x;
    const int tg = t0 + t;
    for (int uc = 0; uc < 1024; uc += 256) {
        #pragma unroll 4
        for (int i = 0; i < 32; ++i) {
            const int u_l = (tid >> 5) + i * 8;
            const int b = tid & 31;
            tile[u_l][b] = hist32[((size_t)t * 1024 + uc + u_l) * 32 + b];
        }
        __syncthreads();
        for (int b = 0; b < 32; ++b) {
            out[((size_t)b * 2048 + tg) * 1024 + uc + tid] = tile[tid][b];
        }
        __syncthreads();
    }
}

// ---------------------------------------------------------------------------
extern "C" void kernel_launch(void* const* d_in, const int* in_sizes, int n_in,
                              void* d_out, int out_size, void* d_ws, size_t ws_size,
                              hipStream_t stream)
{
    const float* inp  = (const float*)d_in[0];
    const float* Wi   = (const float*)d_in[1];
    const float* Wh   = (const float*)d_in[2];
    const float* bias = (const float*)d_in[3];
    float* out = (float*)d_out;

    char* ws = (char*)d_ws;
    auto alignup = [](size_t x) { return (x + 255) & ~(size_t)255; };

    size_t off = 0;
    const size_t ctrl_off = off; off = alignup(off + 4096);
    const size_t c_off    = off; off = alignup(off + (size_t)32 * 1024 * 4);
    const size_t wiT_off  = off; off = alignup(off + (size_t)4096 * 1024 * 2);
    const size_t whT_off  = off; off = alignup(off + (size_t)4096 * 1024 * 2);
    const size_t fixed_end = off;

    // choose largest T-chunk that fits the workspace
    int Tc = 16;
    const int cands[8] = {2048, 1024, 512, 256, 128, 64, 32, 16};
    for (int i = 0; i < 8; ++i) {
        const int c = cands[i];
        size_t need = fixed_end;
        need = alignup(need + (size_t)c * 32 * 1024 * 2);     // A_bf
        need = alignup(need + (size_t)c * 32 * 4096 * 2);     // xw
        need = alignup(need + ((size_t)c + 1) * 32768 * 2);   // h_hist
        need = alignup(need + (size_t)c * 1024 * 32 * 4);     // hist32
        if (need <= ws_size) { Tc = c; break; }
    }
    const size_t a_off   = fixed_end;
    const size_t xw_off  = alignup(a_off  + (size_t)Tc * 32 * 1024 * 2);
    const size_t hh_off  = alignup(xw_off + (size_t)Tc * 32 * 4096 * 2);
    const size_t h32_off = alignup(hh_off + ((size_t)Tc + 1) * 32768 * 2);

    u16*  WiT    = (u16*)(ws + wiT_off);
    u16*  WhT    = (u16*)(ws + whT_off);
    u16*  A_bf   = (u16*)(ws + a_off);
    u16*  xwp    = (u16*)(ws + xw_off);
    u16*  h_hist = (u16*)(ws + hh_off);
    float* hist32 = (float*)(ws + h32_off);
    float* c_buf  = (float*)(ws + c_off);
    unsigned int* ctrl = (unsigned int*)(ws + ctrl_off);

    // one-time weight prep + state init
    transpose_w<<<dim3(128, 32), dim3(32, 8), 0, stream>>>(Wi, WiT);
    transpose_w<<<dim3(128, 32), dim3(32, 8), 0, stream>>>(Wh, WhT);
    hipMemsetAsync(ws + c_off, 0, (size_t)32 * 1024 * 4, stream);
    hipMemsetAsync(ws + hh_off, 0, 65536, stream);

    const int nchunk = 2048 / Tc;
    for (int c = 0; c < nchunk; ++c) {
        const int t0 = c * Tc;
        convert_inputs<<<Tc * 32, 256, 0, stream>>>(inp, A_bf, t0);
        gemm_xw<<<(Tc * 32 / 128) * 32, 256, 0, stream>>>(A_bf, WiT, bias, xwp);
        hipMemsetAsync(ws + ctrl_off, 0, 4096, stream);
        lstm_rec<<<256, 256, 0, stream>>>(xwp, WhT, h_hist, hist32, c_buf, ctrl, Tc);
        emit_out<<<Tc, 256, 0, stream>>>(hist32, out, t0);
        if (c + 1 < nchunk) {
            hipMemcpyAsync(h_hist, h_hist + (size_t)Tc * 32768, 65536,
                           hipMemcpyDeviceToDevice, stream);
        }
    }
}

// Round 2
// 35469.354 us; speedup vs baseline: 1.2038x; 1.2038x over previous
//
#include <hip/hip_runtime.h>
#include <stdint.h>

typedef short bf16x8 __attribute__((ext_vector_type(8)));
typedef float f32x4 __attribute__((ext_vector_type(4)));
typedef unsigned short u16;

__device__ __forceinline__ u16 f2bf(float f) {
    unsigned int u = __float_as_uint(f);
    u = (u + 0x7FFFu + ((u >> 16) & 1u)) >> 16;
    return (u16)u;
}
__device__ __forceinline__ float bf2f(u16 h) {
    return __uint_as_float(((unsigned int)h) << 16);
}
__device__ __forceinline__ float sigm(float x) { return 1.f / (1.f + __expf(-x)); }
__device__ __forceinline__ float tanh_fast(float x) {
    return 1.f - 2.f / (__expf(2.f * x) + 1.f);
}

// ---------------------------------------------------------------------------
// K0: transpose fp32 [1024][4096] weight -> bf16 [4096][1024] (K-contiguous)
// ---------------------------------------------------------------------------
__global__ void transpose_w(const float* __restrict__ src, u16* __restrict__ dst)
{
    __shared__ float tile[32][33];
    const int gx = blockIdx.x;   // over 4096/32
    const int gy = blockIdx.y;   // over 1024/32
    const int tx = threadIdx.x;  // 0..31
    const int ty = threadIdx.y;  // 0..7
    #pragma unroll
    for (int i = 0; i < 4; ++i) {
        const int row = gy * 32 + ty + i * 8;
        tile[ty + i * 8][tx] = src[(size_t)row * 4096 + gx * 32 + tx];
    }
    __syncthreads();
    #pragma unroll
    for (int i = 0; i < 4; ++i) {
        const int row = gx * 32 + ty + i * 8;
        dst[(size_t)row * 1024 + gy * 32 + tx] = f2bf(tile[tx][ty + i * 8]);
    }
}

// ---------------------------------------------------------------------------
// K1: convert input chunk fp32 [B][T][D] -> bf16 rows r = t_local*32 + b
// ---------------------------------------------------------------------------
__global__ void convert_inputs(const float* __restrict__ in, u16* __restrict__ A, const int t0)
{
    const int r = blockIdx.x;          // t*32 + b
    const int t = r >> 5, b = r & 31;
    const int d = threadIdx.x << 2;
    const float4 v = *(const float4*)(in + ((size_t)b * 2048 + t0 + t) * 1024 + d);
    ushort4 o = make_ushort4(f2bf(v.x), f2bf(v.y), f2bf(v.z), f2bf(v.w));
    *(ushort4*)(A + (size_t)r * 1024 + d) = o;
}

// ---------------------------------------------------------------------------
// K2: xw2[t][w][q][eu][eb] = sum_k A[r][k] * WiT[g][k] + bias[g]  (bf16)
//     r = t*32+eb, g = q*1024 + 4*w + eu.  Consumer-optimal layout: one
//     contiguous 1KB block per (t, WG).
// 128x128 tile, BK=32, 4 waves each 64x64, mfma 16x16x32 bf16
// ---------------------------------------------------------------------------
__launch_bounds__(256)
__global__ void gemm_xw(const u16* __restrict__ A, const u16* __restrict__ B,
                        const float* __restrict__ bias, u16* __restrict__ C)
{
    __shared__ u16 As[128 * 32];
    __shared__ u16 Bs[128 * 32];
    const int bm = blockIdx.x >> 5;
    const int bn = blockIdx.x & 31;
    const int tid = threadIdx.x;
    const int wave = tid >> 6, lane = tid & 63;
    const int wr = wave >> 1, wc = wave & 1;
    const int c16 = lane & 15, quad = lane >> 4;

    f32x4 acc[4][4];
    #pragma unroll
    for (int i = 0; i < 4; ++i)
        #pragma unroll
        for (int j = 0; j < 4; ++j) acc[i][j] = (f32x4){0.f, 0.f, 0.f, 0.f};

    const int srow = tid >> 1;
    const int scol = (tid & 1) << 4;
    const u16* Ag = A + (size_t)(bm * 128 + srow) * 1024 + scol;
    const u16* Bg = B + (size_t)(bn * 128 + srow) * 1024 + scol;
    uint4* AsW = (uint4*)(As + srow * 32 + scol);
    uint4* BsW = (uint4*)(Bs + srow * 32 + scol);

    for (int kt = 0; kt < 32; ++kt) {
        const uint4* ag = (const uint4*)(Ag + kt * 32);
        const uint4* bg = (const uint4*)(Bg + kt * 32);
        const uint4 a0 = ag[0], a1 = ag[1];
        const uint4 b0 = bg[0], b1 = bg[1];
        __syncthreads();
        AsW[0] = a0; AsW[1] = a1;
        BsW[0] = b0; BsW[1] = b1;
        __syncthreads();
        bf16x8 af[4], bfr[4];
        #pragma unroll
        for (int mt = 0; mt < 4; ++mt)
            af[mt] = *(const bf16x8*)(As + (wr * 64 + mt * 16 + c16) * 32 + quad * 8);
        #pragma unroll
        for (int nt = 0; nt < 4; ++nt)
            bfr[nt] = *(const bf16x8*)(Bs + (wc * 64 + nt * 16 + c16) * 32 + quad * 8);
        #pragma unroll
        for (int mt = 0; mt < 4; ++mt)
            #pragma unroll
            for (int nt = 0; nt < 4; ++nt)
                acc[mt][nt] = __builtin_amdgcn_mfma_f32_16x16x32_bf16(af[mt], bfr[nt], acc[mt][nt], 0, 0, 0);
    }
    #pragma unroll
    for (int nt = 0; nt < 4; ++nt) {
        const int g = bn * 128 + wc * 64 + nt * 16 + c16;
        const float bv = bias[g];
        const int q  = g >> 10;
        const int u  = g & 1023;
        const int w2 = u >> 2, eu = u & 3;
        #pragma unroll
        for (int mt = 0; mt < 4; ++mt) {
            const int r0 = bm * 128 + wr * 64 + mt * 16 + quad * 4;
            #pragma unroll
            for (int reg = 0; reg < 4; ++reg) {
                const int r = r0 + reg;
                const int t = r >> 5, b = r & 31;
                C[(size_t)(t * 256 + w2) * 512 + q * 128 + eu * 32 + b] =
                    f2bf(acc[mt][nt][reg] + bv);
            }
        }
    }
}

// ---------------------------------------------------------------------------
// K3: persistent recurrence. 256 WGs x 256 thr, 1 WG/CU, co-resident.
// WG w owns hidden units u0..u0+3 (u0=4w).  Wh fragments persistent in
// registers; h read direct-from-global in MFMA A-layout (k-packed).
// Flat all-to-all flag barrier: producer release-stores arrive[w]=t+1;
// every WG's 256 threads poll all 256 flags in parallel (no RMWs),
// then one agent-acquire fence before reading h.
// ---------------------------------------------------------------------------
__launch_bounds__(256)
__global__ void lstm_rec(const u16* __restrict__ xw2, const u16* __restrict__ whT,
                         u16* __restrict__ h_hist, float* __restrict__ hist32,
                         float* __restrict__ c_buf, unsigned int* __restrict__ arrive,
                         const int Tc)
{
    const int w = blockIdx.x;
    const int tid = threadIdx.x;
    const int wave = tid >> 6, lane = tid & 63;
    const int quad = lane >> 4, c16 = lane & 15;
    const int u0 = w << 2;

    // persistent B fragments: local col c16 = q*4+r -> WhT row q*1024+u0+r,
    // wave handles K slice [256*wave, 256*wave+256)
    bf16x8 Breg[8];
    {
        const int q = c16 >> 2, r = c16 & 3;
        const u16* bp = whT + (size_t)(q * 1024 + u0 + r) * 1024 + wave * 256 + quad * 8;
        #pragma unroll
        for (int ks = 0; ks < 8; ++ks) Breg[ks] = *(const bf16x8*)(bp + ks * 32);
    }

    const int eb = tid & 31, eu = tid >> 5;  // epilogue (batch, unit) for tid<128
    float cst = 0.f;
    if (tid < 128) cst = c_buf[eb * 1024 + u0 + eu];

    __shared__ float red[4][32][17];
    __shared__ u16 xbuf[512];

    const int hrow = (w >> 1) * 32;   // k-packed octet-row base for publish
    const int sub  = (w & 1) << 2;

    // prefetch gate block for t=0 (one coalesced dword per thread)
    unsigned int xd = ((const unsigned int*)(xw2 + (size_t)w * 512))[tid];

    for (int t = 0; t < Tc; ++t) {
        if (t > 0) {
            const unsigned int tgt = (unsigned int)t;
            while (__hip_atomic_load(&arrive[tid], __ATOMIC_RELAXED,
                                     __HIP_MEMORY_SCOPE_AGENT) < tgt)
                __builtin_amdgcn_s_sleep(1);
        }
        __syncthreads();
        __builtin_amdgcn_fence(__ATOMIC_ACQUIRE, "agent");

        const u16* hsrc = h_hist + (size_t)t * 32768;
        f32x4 acc0 = (f32x4){0.f, 0.f, 0.f, 0.f};
        f32x4 acc1 = (f32x4){0.f, 0.f, 0.f, 0.f};
        #pragma unroll
        for (int ks = 0; ks < 8; ++ks) {
            const int octet = wave * 32 + ks * 4 + quad;
            const bf16x8 a0 = *(const bf16x8*)(hsrc + (octet * 32 + c16) * 8);
            const bf16x8 a1 = *(const bf16x8*)(hsrc + (octet * 32 + 16 + c16) * 8);
            acc0 = __builtin_amdgcn_mfma_f32_16x16x32_bf16(a0, Breg[ks], acc0, 0, 0, 0);
            acc1 = __builtin_amdgcn_mfma_f32_16x16x32_bf16(a1, Breg[ks], acc1, 0, 0, 0);
        }

        // prefetch next step's gate block (hidden behind next barrier wait)
        unsigned int xd_next = 0;
        if (t + 1 < Tc)
            xd_next = ((const unsigned int*)(xw2 + ((size_t)(t + 1) * 256 + w) * 512))[tid];

        // K-split partials -> LDS (C layout: col=c16, row=quad*4+reg)
        #pragma unroll
        for (int reg = 0; reg < 4; ++reg) {
            red[wave][quad * 4 + reg][c16] = acc0[reg];
            red[wave][16 + quad * 4 + reg][c16] = acc1[reg];
        }
        ((unsigned int*)xbuf)[tid] = xd;
        __syncthreads();

        if (tid < 128) {
            float z[4];
            #pragma unroll
            for (int q = 0; q < 4; ++q) {
                const int c = (q << 2) + eu;
                z[q] = red[0][eb][c] + red[1][eb][c] + red[2][eb][c] + red[3][eb][c]
                     + bf2f(xbuf[q * 128 + eu * 32 + eb]);
            }
            const float ig = sigm(z[0]);
            const float fg = sigm(z[1]);
            const float gg = tanh_fast(z[2]);
            const float og = sigm(z[3]);
            cst = fg * cst + ig * gg;
            const float h = og * tanh_fast(cst);
            hist32[(size_t)(t * 1024 + u0 + eu) * 32 + eb] = h;  // coalesced [t][u][b]
            // publish bf16 h slice, k-packed, straight to LLC (agent scope)
            u16* dst = h_hist + (size_t)(t + 1) * 32768 + (size_t)(hrow + eb) * 8 + sub + eu;
            __hip_atomic_store(dst, f2bf(h), __ATOMIC_RELAXED, __HIP_MEMORY_SCOPE_AGENT);
        }
        __syncthreads();  // drains vmcnt(0): h stores complete at LLC
        if (tid == 0)
            __hip_atomic_store(&arrive[w], (unsigned int)(t + 1),
                               __ATOMIC_RELEASE, __HIP_MEMORY_SCOPE_AGENT);
        xd = xd_next;
    }
    if (tid < 128) c_buf[eb * 1024 + u0 + eu] = cst;
}

// ---------------------------------------------------------------------------
// K4: emit d_out[b][t][u] fp32 from hist32[t][u][b] via LDS transpose
// ---------------------------------------------------------------------------
__launch_bounds__(256)
__global__ void emit_out(const float* __restrict__ hist32, float* __restrict__ out, const int t0)
{
    __shared__ float tile[256][33];
    const int t = blockIdx.x;
    const int tid = threadIdx.x;
    const int tg = t0 + t;
    for (int uc = 0; uc < 1024; uc += 256) {
        #pragma unroll 4
        for (int i = 0; i < 32; ++i) {
            const int u_l = (tid >> 5) + i * 8;
            const int b = tid & 31;
            tile[u_l][b] = hist32[((size_t)t * 1024 + uc + u_l) * 32 + b];
        }
        __syncthreads();
        for (int b = 0; b < 32; ++b) {
            out[((size_t)b * 2048 + tg) * 1024 + uc + tid] = tile[tid][b];
        }
        __syncthreads();
    }
}

// ---------------------------------------------------------------------------
extern "C" void kernel_launch(void* const* d_in, const int* in_sizes, int n_in,
                              void* d_out, int out_size, void* d_ws, size_t ws_size,
                              hipStream_t stream)
{
    const float* inp  = (const float*)d_in[0];
    const float* Wi   = (const float*)d_in[1];
    const float* Wh   = (const float*)d_in[2];
    const float* bias = (const float*)d_in[3];
    float* out = (float*)d_out;

    char* ws = (char*)d_ws;
    auto alignup = [](size_t x) { return (x + 255) & ~(size_t)255; };

    size_t off = 0;
    const size_t ctrl_off = off; off = alignup(off + 4096);
    const size_t c_off    = off; off = alignup(off + (size_t)32 * 1024 * 4);
    const size_t wiT_off  = off; off = alignup(off + (size_t)4096 * 1024 * 2);
    const size_t whT_off  = off; off = alignup(off + (size_t)4096 * 1024 * 2);
    const size_t fixed_end = off;

    // choose largest T-chunk that fits the workspace
    int Tc = 16;
    const int cands[8] = {2048, 1024, 512, 256, 128, 64, 32, 16};
    for (int i = 0; i < 8; ++i) {
        const int c = cands[i];
        size_t need = fixed_end;
        need = alignup(need + (size_t)c * 32 * 1024 * 2);     // A_bf
        need = alignup(need + (size_t)c * 32 * 4096 * 2);     // xw2
        need = alignup(need + ((size_t)c + 1) * 32768 * 2);   // h_hist
        need = alignup(need + (size_t)c * 1024 * 32 * 4);     // hist32
        if (need <= ws_size) { Tc = c; break; }
    }
    const size_t a_off   = fixed_end;
    const size_t xw_off  = alignup(a_off  + (size_t)Tc * 32 * 1024 * 2);
    const size_t hh_off  = alignup(xw_off + (size_t)Tc * 32 * 4096 * 2);
    const size_t h32_off = alignup(hh_off + ((size_t)Tc + 1) * 32768 * 2);

    u16*  WiT    = (u16*)(ws + wiT_off);
    u16*  WhT    = (u16*)(ws + whT_off);
    u16*  A_bf   = (u16*)(ws + a_off);
    u16*  xwp    = (u16*)(ws + xw_off);
    u16*  h_hist = (u16*)(ws + hh_off);
    float* hist32 = (float*)(ws + h32_off);
    float* c_buf  = (float*)(ws + c_off);
    unsigned int* ctrl = (unsigned int*)(ws + ctrl_off);

    // one-time weight prep + state init
    transpose_w<<<dim3(128, 32), dim3(32, 8), 0, stream>>>(Wi, WiT);
    transpose_w<<<dim3(128, 32), dim3(32, 8), 0, stream>>>(Wh, WhT);
    hipMemsetAsync(ws + c_off, 0, (size_t)32 * 1024 * 4, stream);
    hipMemsetAsync(ws + hh_off, 0, 65536, stream);

    const int nchunk = 2048 / Tc;
    for (int c = 0; c < nchunk; ++c) {
        const int t0 = c * Tc;
        convert_inputs<<<Tc * 32, 256, 0, stream>>>(inp, A_bf, t0);
        gemm_xw<<<(Tc * 32 / 128) * 32, 256, 0, stream>>>(A_bf, WiT, bias, xwp);
        hipMemsetAsync(ws + ctrl_off, 0, 4096, stream);
        lstm_rec<<<256, 256, 0, stream>>>(xwp, WhT, h_hist, hist32, c_buf, ctrl, Tc);
        emit_out<<<Tc, 256, 0, stream>>>(hist32, out, t0);
        if (c + 1 < nchunk) {
            hipMemcpyAsync(h_hist, h_hist + (size_t)Tc * 32768, 65536,
                           hipMemcpyDeviceToDevice, stream);
        }
    }
}